// Round 3
// baseline (149.046 us; speedup 1.0000x reference)
//
#include <hip/hip_runtime.h>
#include <hip/hip_bf16.h>

typedef unsigned short u16;
typedef __attribute__((ext_vector_type(8))) __bf16 bf16x8;
typedef __attribute__((ext_vector_type(4))) float f32x4;
typedef __attribute__((ext_vector_type(4))) unsigned short u16x4;

#define SEQ 4096
#define DIM 1024
#define NH 16
#define HD 64
#define WIN 256

__device__ inline u16 f2bf(float f) {
  __hip_bfloat16 h = __float2bfloat16(f);
  return __builtin_bit_cast(u16, h);
}

__device__ inline void gload_lds16(const void* g, void* l) {
  auto gp = reinterpret_cast<__attribute__((address_space(1))) unsigned int*>(
      reinterpret_cast<unsigned long long>(g));
  auto lp = reinterpret_cast<__attribute__((address_space(3))) unsigned int*>(
      reinterpret_cast<unsigned long long>(l));
  __builtin_amdgcn_global_load_lds(gp, lp, 16, 0, 0);
}

__global__ __launch_bounds__(256) void cast4(const float* __restrict__ in,
                                             u16* __restrict__ out, int n) {
  int i = (blockIdx.x * 256 + threadIdx.x) * 4;
  if (i >= n) return;
  const float4 v = *reinterpret_cast<const float4*>(in + i);
  u16x4 r;
  r.x = f2bf(v.x); r.y = f2bf(v.y); r.z = f2bf(v.z); r.w = f2bf(v.w);
  *reinterpret_cast<u16x4*>(out + i) = r;
}

// Fused QKV projection: A = H [4096][1024] bf16, B = concat(Wq,Wk,Wv) [3072][1024] bf16.
// C[m][n] = sum_k A[m][k]*B[n][k] + bias[n].  Cols 0-1023 -> Qb (x0.125),
// 1024-2047 -> Kb, 2048-3071 -> Vt TRANSPOSED ([d][seq]).
// Tile 128x128, BK=64, 4 waves each 64x64. XCD-aware block swizzle (768%8==0).
__global__ __launch_bounds__(256) void gemm_qkv(const u16* __restrict__ A, const u16* __restrict__ B,
                                                const float* __restrict__ bias,
                                                u16* __restrict__ Qb, u16* __restrict__ Kb,
                                                u16* __restrict__ Vt) {
  const int K = DIM;
  __shared__ __align__(16) u16 As[128 * 64];
  __shared__ __align__(16) u16 Bs[128 * 64];
  const int nwgx = gridDim.x;                       // 24
  const int nwg = nwgx * gridDim.y;                 // 768
  const int orig = blockIdx.y * nwgx + blockIdx.x;
  const int cpx = nwg >> 3;                         // 96
  const int wgid = (orig & 7) * cpx + (orig >> 3);  // bijective (768%8==0)
  const int bm = (wgid / nwgx) * 128, bn = (wgid % nwgx) * 128;
  const int tid = threadIdx.x;
  const int wid = tid >> 6, lane = tid & 63;
  const int lrow = lane & 15, lgrp = lane >> 4;
  const int wr = (wid >> 1) * 64, wc = (wid & 1) * 64;
  f32x4 zero = {0.f, 0.f, 0.f, 0.f};
  f32x4 acc[4][4];
#pragma unroll
  for (int i = 0; i < 4; ++i)
#pragma unroll
    for (int j = 0; j < 4; ++j) acc[i][j] = zero;

  for (int k0 = 0; k0 < K; k0 += 64) {
    __syncthreads();
#pragma unroll
    for (int it = 0; it < 4; ++it) {
      const int base = it * 2048 + wid * 512;  // element offset of wave segment
      const int f = base + lane * 8;
      const int r = f >> 6, c = f & 63;
      gload_lds16(A + (size_t)(bm + r) * K + k0 + c, &As[base]);
      gload_lds16(B + (size_t)(bn + r) * K + k0 + c, &Bs[base]);
    }
    __syncthreads();
#pragma unroll
    for (int ks = 0; ks < 2; ++ks) {
      bf16x8 af[4], bfr[4];
#pragma unroll
      for (int i = 0; i < 4; ++i)
        af[i] = *reinterpret_cast<const bf16x8*>(&As[(wr + i * 16 + lrow) * 64 + ks * 32 + lgrp * 8]);
#pragma unroll
      for (int j = 0; j < 4; ++j)
        bfr[j] = *reinterpret_cast<const bf16x8*>(&Bs[(wc + j * 16 + lrow) * 64 + ks * 32 + lgrp * 8]);
#pragma unroll
      for (int i = 0; i < 4; ++i)
#pragma unroll
        for (int j = 0; j < 4; ++j)
          acc[i][j] = __builtin_amdgcn_mfma_f32_16x16x32_bf16(af[i], bfr[j], acc[i][j], 0, 0, 0);
    }
  }
#pragma unroll
  for (int i = 0; i < 4; ++i)
#pragma unroll
    for (int j = 0; j < 4; ++j) {
      const int row0 = bm + wr + i * 16 + lgrp * 4;
      const int colg = bn + wc + j * 16 + lrow;
      const float b = bias[colg];
      if (bn < 2048) {
        u16* dst = (bn < 1024) ? Qb : Kb;
        const float sc = (bn < 1024) ? 0.125f : 1.0f;
        const int c = colg & 1023;
#pragma unroll
        for (int r = 0; r < 4; ++r)
          dst[(size_t)(row0 + r) * DIM + c] = f2bf((acc[i][j][r] + b) * sc);
      } else {
        const int dv = colg - 2048;
        u16x4 pk;
#pragma unroll
        for (int r = 0; r < 4; ++r) pk[r] = f2bf(acc[i][j][r] + b);
        *reinterpret_cast<u16x4*>(Vt + (size_t)dv * SEQ + row0) = pk;
      }
    }
}

// Banded flash attention, deferred softmax, SPLIT-K across wave pairs.
// Q,K: [S][1024] bf16 (head h = cols h*64..h*64+63), Vt: [1024][S] bf16.
// Block: (32 queries, head) -> 4 waves = 2 q-tiles x 2 key-halves.
__global__ __launch_bounds__(256) void lf_attn(const u16* __restrict__ Q, const u16* __restrict__ Kb,
                                               const u16* __restrict__ Vt, const float* __restrict__ amask,
                                               float* __restrict__ out) {
  const int nwgx = gridDim.x;                       // 128
  const int nwg = nwgx * gridDim.y;                 // 2048
  const int orig = blockIdx.y * nwgx + blockIdx.x;
  const int cpx = nwg >> 3;                         // 256
  const int wgid = (orig & 7) * cpx + (orig >> 3);  // bijective (2048%8==0)
  const int h = wgid / nwgx;
  const int q0 = (wgid % nwgx) * 32;
  const int tid = threadIdx.x;
  const int wid = tid >> 6, lane = tid & 63;
  const int qt = wid & 1, kh = wid >> 1;
  const int lrow = lane & 15, lgrp = lane >> 4;
  const int qw = q0 + qt * 16;
  __shared__ __align__(16) u16 Plds[4][16][32];
  __shared__ __align__(16) float Ocmb[2][16][64];
  __shared__ float Pscmb[2][16];

  bf16x8 qf0, qf1;
  {
    const u16* qbase = Q + (size_t)(qw + lrow) * DIM + h * HD + lgrp * 8;
    qf0 = *reinterpret_cast<const bf16x8*>(qbase);
    qf1 = *reinterpret_cast<const bf16x8*>(qbase + 32);
  }
  f32x4 zero = {0.f, 0.f, 0.f, 0.f};
  f32x4 o_acc[4];
  float ps[4];
#pragma unroll
  for (int r = 0; r < 4; ++r) ps[r] = 0.f;
#pragma unroll
  for (int g = 0; g < 4; ++g) o_acc[g] = zero;

  int kstart = qw - WIN; if (kstart < 0) kstart = 0; kstart &= ~31;
  int kend = qw + 15 + WIN + 1; kend = (kend + 31) & ~31; if (kend > SEQ) kend = SEQ;
  const int nt = (kend - kstart) >> 5;
  const int hf = (nt + 1) >> 1;
  const int tbeg = kh ? hf : 0;
  const int tend = kh ? nt : hf;

  for (int t = tbeg; t < tend; ++t) {
    const int kt = kstart + t * 32;
    const int j0 = kt + lrow;
    const float am0 = (amask[j0] != 0.f) ? -10000.f : 0.f;
    const float am1 = (amask[j0 + 16] != 0.f) ? -10000.f : 0.f;
    f32x4 s0 = zero, s1 = zero;
    {
      const u16* kb0 = Kb + (size_t)(kt + lrow) * DIM + h * HD + lgrp * 8;
      const bf16x8 k00 = *reinterpret_cast<const bf16x8*>(kb0);
      const bf16x8 k01 = *reinterpret_cast<const bf16x8*>(kb0 + 32);
      const bf16x8 k10 = *reinterpret_cast<const bf16x8*>(kb0 + 16 * DIM);
      const bf16x8 k11 = *reinterpret_cast<const bf16x8*>(kb0 + 16 * DIM + 32);
      s0 = __builtin_amdgcn_mfma_f32_16x16x32_bf16(qf0, k00, s0, 0, 0, 0);
      s0 = __builtin_amdgcn_mfma_f32_16x16x32_bf16(qf1, k01, s0, 0, 0, 0);
      s1 = __builtin_amdgcn_mfma_f32_16x16x32_bf16(qf0, k10, s1, 0, 0, 0);
      s1 = __builtin_amdgcn_mfma_f32_16x16x32_bf16(qf1, k11, s1, 0, 0, 0);
    }
#pragma unroll
    for (int r = 0; r < 4; ++r) {
      const int i_abs = qw + lgrp * 4 + r;
      const int d0 = j0 - i_abs + WIN;   // valid iff 0 <= d0 <= 2*WIN
      const float e0 = ((unsigned)d0 <= 2u * WIN) ? __expf(s0[r] + am0) : 0.f;
      const float e1 = ((unsigned)(d0 + 16) <= 2u * WIN) ? __expf(s1[r] + am1) : 0.f;
      ps[r] += e0 + e1;
      Plds[wid][lgrp * 4 + r][lrow] = f2bf(e0);
      Plds[wid][lgrp * 4 + r][lrow + 16] = f2bf(e1);
    }
    const bf16x8 pf = *reinterpret_cast<const bf16x8*>(&Plds[wid][lrow][lgrp * 8]);
    const u16* vb = Vt + (size_t)(h * HD + lrow) * SEQ + kt + lgrp * 8;
#pragma unroll
    for (int g = 0; g < 4; ++g) {
      const bf16x8 vf = *reinterpret_cast<const bf16x8*>(vb + (size_t)g * 16 * SEQ);
      o_acc[g] = __builtin_amdgcn_mfma_f32_16x16x32_bf16(pf, vf, o_acc[g], 0, 0, 0);
    }
  }

  // 16-lane row-sum reduce of ps (each lane then holds the full row sum).
#pragma unroll
  for (int r = 0; r < 4; ++r) {
#pragma unroll
    for (int off = 1; off < 16; off <<= 1) ps[r] += __shfl_xor(ps[r], off, 16);
  }

  // Combine the two key-halves of each q-tile.
  if (kh == 1) {
#pragma unroll
    for (int g = 0; g < 4; ++g)
#pragma unroll
      for (int r = 0; r < 4; ++r)
        Ocmb[qt][lgrp * 4 + r][g * 16 + lrow] = o_acc[g][r];
    if (lrow == 0) {
#pragma unroll
      for (int r = 0; r < 4; ++r) Pscmb[qt][lgrp * 4 + r] = ps[r];
    }
  }
  __syncthreads();
  if (kh == 0) {
#pragma unroll
    for (int g = 0; g < 4; ++g)
#pragma unroll
      for (int r = 0; r < 4; ++r) {
        const int row = qw + lgrp * 4 + r;
        const float o = o_acc[g][r] + Ocmb[qt][lgrp * 4 + r][g * 16 + lrow];
        const float l = ps[r] + Pscmb[qt][lgrp * 4 + r];
        out[(size_t)row * DIM + h * HD + g * 16 + lrow] = o / l;
      }
  }
}

extern "C" void kernel_launch(void* const* d_in, const int* in_sizes, int n_in,
                              void* d_out, int out_size, void* d_ws, size_t ws_size,
                              hipStream_t stream) {
  const float* hsrc  = (const float*)d_in[0];
  const float* amask = (const float*)d_in[1];
  const float* Wq = (const float*)d_in[3];
  const float* bq = (const float*)d_in[4];
  const float* Wk = (const float*)d_in[5];
  const float* bk = (const float*)d_in[6];
  const float* Wv = (const float*)d_in[7];
  const float* bv = (const float*)d_in[8];
  float* out = (float*)d_out;
  char* ws = (char*)d_ws;
  const size_t MB = 1024 * 1024;
  u16*   Hb      = (u16*)(ws);                 // 8 MB: hidden bf16 [4096][1024]
  u16*   Wcat    = (u16*)(ws + 8 * MB);        // 6 MB: [3072][1024] bf16 (Wq|Wk|Wv)
  float* biascat = (float*)(ws + 14 * MB);     // 12 KB: [3072] f32
  u16*   Qb      = (u16*)(ws + 15 * MB);       // 8 MB: [4096][1024] (pre-scaled)
  u16*   Kbf     = (u16*)(ws + 23 * MB);       // 8 MB: [4096][1024]
  u16*   Vt      = (u16*)(ws + 31 * MB);       // 8 MB: [1024][4096] (transposed V)

  cast4<<<4096, 256, 0, stream>>>(hsrc, Hb, SEQ * DIM);
  cast4<<<1024, 256, 0, stream>>>(Wq, Wcat, DIM * DIM);
  cast4<<<1024, 256, 0, stream>>>(Wk, Wcat + DIM * DIM, DIM * DIM);
  cast4<<<1024, 256, 0, stream>>>(Wv, Wcat + 2 * DIM * DIM, DIM * DIM);
  hipMemcpyAsync(biascat,            bq, DIM * sizeof(float), hipMemcpyDeviceToDevice, stream);
  hipMemcpyAsync(biascat + DIM,      bk, DIM * sizeof(float), hipMemcpyDeviceToDevice, stream);
  hipMemcpyAsync(biascat + 2 * DIM,  bv, DIM * sizeof(float), hipMemcpyDeviceToDevice, stream);

  dim3 gq(3 * DIM / 128, SEQ / 128);  // (24, 32)
  gemm_qkv<<<gq, 256, 0, stream>>>(Hb, Wcat, biascat, Qb, Kbf, Vt);

  dim3 ga(SEQ / 32, NH);              // (128, 16)
  lf_attn<<<ga, 256, 0, stream>>>(Qb, Kbf, Vt, amask, out);
}

// Round 4
// 133.188 us; speedup vs baseline: 1.1191x; 1.1191x over previous
//
#include <hip/hip_runtime.h>
#include <hip/hip_bf16.h>

typedef unsigned short u16;
typedef __attribute__((ext_vector_type(8))) __bf16 bf16x8;
typedef __attribute__((ext_vector_type(4))) float f32x4;
typedef __attribute__((ext_vector_type(4))) unsigned short u16x4;

#define SEQ 4096
#define DIM 1024
#define NH 16
#define HD 64
#define WIN 256
#define NT32 (SEQ / 32)

__device__ inline u16 f2bf(float f) {
  __hip_bfloat16 h = __float2bfloat16(f);
  return __builtin_bit_cast(u16, h);
}

__device__ inline void gload_lds16(const void* g, void* l) {
  auto gp = reinterpret_cast<__attribute__((address_space(1))) unsigned int*>(
      reinterpret_cast<unsigned long long>(g));
  auto lp = reinterpret_cast<__attribute__((address_space(3))) unsigned int*>(
      reinterpret_cast<unsigned long long>(l));
  __builtin_amdgcn_global_load_lds(gp, lp, 16, 0, 0);
}

__global__ __launch_bounds__(256) void cast4(const float* __restrict__ in,
                                             u16* __restrict__ out, int n) {
  int i = (blockIdx.x * 256 + threadIdx.x) * 4;
  if (i >= n) return;
  const float4 v = *reinterpret_cast<const float4*>(in + i);
  u16x4 r;
  r.x = f2bf(v.x); r.y = f2bf(v.y); r.z = f2bf(v.z); r.w = f2bf(v.w);
  *reinterpret_cast<u16x4*>(out + i) = r;
}

// Fused QKV projection: A = H [4096][1024] bf16, B = concat(Wq,Wk,Wv) [3072][1024] bf16.
// C[m][n] = sum_k A[m][k]*B[n][k] + bias[n].
// Cols 0-1023   -> Qh [NH][S][64] (x0.125)
// Cols 1024-2047-> Kh [NH][S][64]
// Cols 2048-3071-> Vtile [NH][S/32][64][32]  (key-contiguous 4KB tiles)
// Tile 128x128, BK=64, 4 waves each 64x64. XCD-aware block swizzle (768%8==0).
__global__ __launch_bounds__(256) void gemm_qkv(const u16* __restrict__ A, const u16* __restrict__ B,
                                                const float* __restrict__ bias,
                                                u16* __restrict__ Qh, u16* __restrict__ Kh,
                                                u16* __restrict__ Vtile) {
  const int K = DIM;
  __shared__ __align__(16) u16 As[128 * 64];
  __shared__ __align__(16) u16 Bs[128 * 64];
  const int nwgx = gridDim.x;                       // 24
  const int nwg = nwgx * gridDim.y;                 // 768
  const int orig = blockIdx.y * nwgx + blockIdx.x;
  const int cpx = nwg >> 3;                         // 96
  const int wgid = (orig & 7) * cpx + (orig >> 3);  // bijective (768%8==0)
  const int bm = (wgid / nwgx) * 128, bn = (wgid % nwgx) * 128;
  const int tid = threadIdx.x;
  const int wid = tid >> 6, lane = tid & 63;
  const int lrow = lane & 15, lgrp = lane >> 4;
  const int wr = (wid >> 1) * 64, wc = (wid & 1) * 64;
  f32x4 zero = {0.f, 0.f, 0.f, 0.f};
  f32x4 acc[4][4];
#pragma unroll
  for (int i = 0; i < 4; ++i)
#pragma unroll
    for (int j = 0; j < 4; ++j) acc[i][j] = zero;

  for (int k0 = 0; k0 < K; k0 += 64) {
    __syncthreads();
#pragma unroll
    for (int it = 0; it < 4; ++it) {
      const int base = it * 2048 + wid * 512;  // element offset of wave segment
      const int f = base + lane * 8;
      const int r = f >> 6, c = f & 63;
      gload_lds16(A + (size_t)(bm + r) * K + k0 + c, &As[base]);
      gload_lds16(B + (size_t)(bn + r) * K + k0 + c, &Bs[base]);
    }
    __syncthreads();
#pragma unroll
    for (int ks = 0; ks < 2; ++ks) {
      bf16x8 af[4], bfr[4];
#pragma unroll
      for (int i = 0; i < 4; ++i)
        af[i] = *reinterpret_cast<const bf16x8*>(&As[(wr + i * 16 + lrow) * 64 + ks * 32 + lgrp * 8]);
#pragma unroll
      for (int j = 0; j < 4; ++j)
        bfr[j] = *reinterpret_cast<const bf16x8*>(&Bs[(wc + j * 16 + lrow) * 64 + ks * 32 + lgrp * 8]);
#pragma unroll
      for (int i = 0; i < 4; ++i)
#pragma unroll
        for (int j = 0; j < 4; ++j)
          acc[i][j] = __builtin_amdgcn_mfma_f32_16x16x32_bf16(af[i], bfr[j], acc[i][j], 0, 0, 0);
    }
  }
#pragma unroll
  for (int i = 0; i < 4; ++i)
#pragma unroll
    for (int j = 0; j < 4; ++j) {
      const int row0 = bm + wr + i * 16 + lgrp * 4;
      const int colg = bn + wc + j * 16 + lrow;
      const float b = bias[colg];
      if (bn < 2048) {
        u16* dst = (bn < 1024) ? Qh : Kh;
        const float sc = (bn < 1024) ? 0.125f : 1.0f;
        const int hh = (colg & 1023) >> 6;
        const int dd = colg & 63;
#pragma unroll
        for (int r = 0; r < 4; ++r)
          dst[((size_t)hh * SEQ + row0 + r) * HD + dd] = f2bf((acc[i][j][r] + b) * sc);
      } else {
        const int dv = colg - 2048;
        const int hh = dv >> 6, dd = dv & 63;
        u16x4 pk;
#pragma unroll
        for (int r = 0; r < 4; ++r) pk[r] = f2bf(acc[i][j][r] + b);
        u16* vt = Vtile + ((((size_t)hh * NT32 + (row0 >> 5)) * HD + dd) << 5) + (row0 & 31);
        *reinterpret_cast<u16x4*>(vt) = pk;
      }
    }
}

// Banded flash attention, deferred softmax, SPLIT-K across wave pairs.
// Qh,Kh: [NH][S][64] bf16; Vtile: [NH][S/32][64][32] bf16.
// Block: (32 queries, head) -> 4 waves = 2 q-tiles x 2 key-halves.
__global__ __launch_bounds__(256) void lf_attn(const u16* __restrict__ Qh, const u16* __restrict__ Kh,
                                               const u16* __restrict__ Vtile, const float* __restrict__ amask,
                                               float* __restrict__ out) {
  const int nwgx = gridDim.x;                       // 128
  const int nwg = nwgx * gridDim.y;                 // 2048
  const int orig = blockIdx.y * nwgx + blockIdx.x;
  const int cpx = nwg >> 3;                         // 256
  const int wgid = (orig & 7) * cpx + (orig >> 3);  // bijective (2048%8==0)
  const int h = wgid / nwgx;
  const int q0 = (wgid % nwgx) * 32;
  const int tid = threadIdx.x;
  const int wid = tid >> 6, lane = tid & 63;
  const int qt = wid & 1, kh = wid >> 1;
  const int lrow = lane & 15, lgrp = lane >> 4;
  const int qw = q0 + qt * 16;
  __shared__ __align__(16) u16 Plds[4][16][32];
  __shared__ __align__(16) float Ocmb[2][16][64];
  __shared__ float Pscmb[2][16];

  bf16x8 qf0, qf1;
  {
    const u16* qbase = Qh + ((size_t)h * SEQ + qw + lrow) * HD + lgrp * 8;
    qf0 = *reinterpret_cast<const bf16x8*>(qbase);
    qf1 = *reinterpret_cast<const bf16x8*>(qbase + 32);
  }
  f32x4 zero = {0.f, 0.f, 0.f, 0.f};
  f32x4 o_acc[4];
  float ps[4];
#pragma unroll
  for (int r = 0; r < 4; ++r) ps[r] = 0.f;
#pragma unroll
  for (int g = 0; g < 4; ++g) o_acc[g] = zero;

  int kstart = qw - WIN; if (kstart < 0) kstart = 0; kstart &= ~31;
  int kend = qw + 15 + WIN + 1; kend = (kend + 31) & ~31; if (kend > SEQ) kend = SEQ;
  const int nt = (kend - kstart) >> 5;
  const int hf = (nt + 1) >> 1;
  const int tbeg = kh ? hf : 0;
  const int tend = kh ? nt : hf;

  for (int t = tbeg; t < tend; ++t) {
    const int kt = kstart + t * 32;
    const int j0 = kt + lrow;
    // K fragment loads: 1KB contiguous per instruction.
    const u16* kb0 = Kh + ((size_t)h * SEQ + kt + lrow) * HD + lgrp * 8;
    const bf16x8 k00 = *reinterpret_cast<const bf16x8*>(kb0);
    const bf16x8 k01 = *reinterpret_cast<const bf16x8*>(kb0 + 32);
    const bf16x8 k10 = *reinterpret_cast<const bf16x8*>(kb0 + 16 * HD);
    const bf16x8 k11 = *reinterpret_cast<const bf16x8*>(kb0 + 16 * HD + 32);
    // V fragment prefetch: contiguous 4KB tile.
    const u16* vb = Vtile + (((size_t)h * NT32 + (kt >> 5)) * HD << 5) + lrow * 32 + lgrp * 8;
    bf16x8 vf[4];
#pragma unroll
    for (int g = 0; g < 4; ++g)
      vf[g] = *reinterpret_cast<const bf16x8*>(vb + g * 16 * 32);
    f32x4 s0 = zero, s1 = zero;
    s0 = __builtin_amdgcn_mfma_f32_16x16x32_bf16(qf0, k00, s0, 0, 0, 0);
    s0 = __builtin_amdgcn_mfma_f32_16x16x32_bf16(qf1, k01, s0, 0, 0, 0);
    s1 = __builtin_amdgcn_mfma_f32_16x16x32_bf16(qf0, k10, s1, 0, 0, 0);
    s1 = __builtin_amdgcn_mfma_f32_16x16x32_bf16(qf1, k11, s1, 0, 0, 0);

    const float am0 = (amask[j0] != 0.f) ? -10000.f : 0.f;
    const float am1 = (amask[j0 + 16] != 0.f) ? -10000.f : 0.f;
#pragma unroll
    for (int r = 0; r < 4; ++r) {
      const int i_abs = qw + lgrp * 4 + r;
      const int d0 = j0 - i_abs + WIN;   // valid iff 0 <= d0 <= 2*WIN
      const float e0 = ((unsigned)d0 <= 2u * WIN) ? __expf(s0[r] + am0) : 0.f;
      const float e1 = ((unsigned)(d0 + 16) <= 2u * WIN) ? __expf(s1[r] + am1) : 0.f;
      ps[r] += e0 + e1;
      Plds[wid][lgrp * 4 + r][lrow] = f2bf(e0);
      Plds[wid][lgrp * 4 + r][lrow + 16] = f2bf(e1);
    }
    const bf16x8 pf = *reinterpret_cast<const bf16x8*>(&Plds[wid][lrow][lgrp * 8]);
#pragma unroll
    for (int g = 0; g < 4; ++g)
      o_acc[g] = __builtin_amdgcn_mfma_f32_16x16x32_bf16(pf, vf[g], o_acc[g], 0, 0, 0);
  }

  // 16-lane row-sum reduce of ps (each lane then holds the full row sum).
#pragma unroll
  for (int r = 0; r < 4; ++r) {
#pragma unroll
    for (int off = 1; off < 16; off <<= 1) ps[r] += __shfl_xor(ps[r], off, 16);
  }

  // Combine the two key-halves of each q-tile.
  if (kh == 1) {
#pragma unroll
    for (int g = 0; g < 4; ++g)
#pragma unroll
      for (int r = 0; r < 4; ++r)
        Ocmb[qt][lgrp * 4 + r][g * 16 + lrow] = o_acc[g][r];
    if (lrow == 0) {
#pragma unroll
      for (int r = 0; r < 4; ++r) Pscmb[qt][lgrp * 4 + r] = ps[r];
    }
  }
  __syncthreads();
  if (kh == 0) {
#pragma unroll
    for (int g = 0; g < 4; ++g)
#pragma unroll
      for (int r = 0; r < 4; ++r) {
        const int row = qw + lgrp * 4 + r;
        const float o = o_acc[g][r] + Ocmb[qt][lgrp * 4 + r][g * 16 + lrow];
        const float l = ps[r] + Pscmb[qt][lgrp * 4 + r];
        out[(size_t)row * DIM + h * HD + g * 16 + lrow] = o / l;
      }
  }
}

extern "C" void kernel_launch(void* const* d_in, const int* in_sizes, int n_in,
                              void* d_out, int out_size, void* d_ws, size_t ws_size,
                              hipStream_t stream) {
  const float* hsrc  = (const float*)d_in[0];
  const float* amask = (const float*)d_in[1];
  const float* Wq = (const float*)d_in[3];
  const float* bq = (const float*)d_in[4];
  const float* Wk = (const float*)d_in[5];
  const float* bk = (const float*)d_in[6];
  const float* Wv = (const float*)d_in[7];
  const float* bv = (const float*)d_in[8];
  float* out = (float*)d_out;
  char* ws = (char*)d_ws;
  const size_t MB = 1024 * 1024;
  u16*   Hb      = (u16*)(ws);                 // 8 MB: hidden bf16 [4096][1024]
  u16*   Wcat    = (u16*)(ws + 8 * MB);        // 6 MB: [3072][1024] bf16 (Wq|Wk|Wv)
  float* biascat = (float*)(ws + 14 * MB);     // 12 KB: [3072] f32
  u16*   Qh      = (u16*)(ws + 15 * MB);       // 8 MB: [NH][S][64] (pre-scaled)
  u16*   Kh      = (u16*)(ws + 23 * MB);       // 8 MB: [NH][S][64]
  u16*   Vtile   = (u16*)(ws + 31 * MB);       // 8 MB: [NH][S/32][64][32]

  cast4<<<4096, 256, 0, stream>>>(hsrc, Hb, SEQ * DIM);
  cast4<<<1024, 256, 0, stream>>>(Wq, Wcat, DIM * DIM);
  cast4<<<1024, 256, 0, stream>>>(Wk, Wcat + DIM * DIM, DIM * DIM);
  cast4<<<1024, 256, 0, stream>>>(Wv, Wcat + 2 * DIM * DIM, DIM * DIM);
  hipMemcpyAsync(biascat,            bq, DIM * sizeof(float), hipMemcpyDeviceToDevice, stream);
  hipMemcpyAsync(biascat + DIM,      bk, DIM * sizeof(float), hipMemcpyDeviceToDevice, stream);
  hipMemcpyAsync(biascat + 2 * DIM,  bv, DIM * sizeof(float), hipMemcpyDeviceToDevice, stream);

  dim3 gq(3 * DIM / 128, SEQ / 128);  // (24, 32)
  gemm_qkv<<<gq, 256, 0, stream>>>(Hb, Wcat, biascat, Qh, Kh, Vtile);

  dim3 ga(SEQ / 32, NH);              // (128, 16)
  lf_attn<<<ga, 256, 0, stream>>>(Qh, Kh, Vtile, amask, out);
}

// Round 6
// 114.047 us; speedup vs baseline: 1.3069x; 1.1678x over previous
//
#include <hip/hip_runtime.h>
#include <hip/hip_bf16.h>

typedef unsigned short u16;
typedef __attribute__((ext_vector_type(8))) __bf16 bf16x8;
typedef __attribute__((ext_vector_type(4))) float f32x4;
typedef __attribute__((ext_vector_type(4))) unsigned short u16x4;

#define SEQ 4096
#define DIM 1024
#define NH 16
#define HD 64
#define WIN 256
#define NT32 (SEQ / 32)
#define NKT 32  // K-tiles of 32 in K=1024

__device__ inline u16 f2bf(float f) {
  __hip_bfloat16 h = __float2bfloat16(f);
  return __builtin_bit_cast(u16, h);
}

__device__ inline void gload_lds16(const void* g, void* l) {
  auto gp = reinterpret_cast<__attribute__((address_space(1))) unsigned int*>(
      reinterpret_cast<unsigned long long>(g));
  auto lp = reinterpret_cast<__attribute__((address_space(3))) unsigned int*>(
      reinterpret_cast<unsigned long long>(l));
  __builtin_amdgcn_global_load_lds(gp, lp, 16, 0, 0);
}

__global__ __launch_bounds__(256) void cast4(const float* __restrict__ in,
                                             u16* __restrict__ out, int n) {
  int i = (blockIdx.x * 256 + threadIdx.x) * 4;
  if (i >= n) return;
  const float4 v = *reinterpret_cast<const float4*>(in + i);
  u16x4 r;
  r.x = f2bf(v.x); r.y = f2bf(v.y); r.z = f2bf(v.z); r.w = f2bf(v.w);
  *reinterpret_cast<u16x4*>(out + i) = r;
}

// Stage one 256x32 A-panel tile + 256x32 B-panel tile into LDS slot (linear layout,
// 64B rows -> frag ds_read_b128 is naturally bank-conflict-free).
__device__ __forceinline__ void stage_tile(const u16* __restrict__ A, const u16* __restrict__ B,
                                           int bm, int bn, u16* sa, u16* sb, int kt, int tid) {
  const int k0 = kt * 32;
#pragma unroll
  for (int l = 0; l < 2; ++l) {
    const int li = l * 512 + tid;         // 1024 chunks of 16B per matrix
    const int r = li >> 2, c = (li & 3) * 8;
    gload_lds16(A + (size_t)(bm + r) * DIM + k0 + c, sa + li * 8);
    gload_lds16(B + (size_t)(bn + r) * DIM + k0 + c, sb + li * 8);
  }
}

// Fused QKV projection, tri-buffered counted-vmcnt pipeline (T3/T4).
// A = H [4096][1024] bf16, B = concat(Wq,Wk,Wv) [3072][1024] bf16.
// C[m][n] = sum_k A[m][k]*B[n][k] + bias[n].
// Cols 0-1023    -> Qh [NH][S][64]  (x 0.125/ln2, exp2 trick)
// Cols 1024-2047 -> Kh [NH][S][64]
// Cols 2048-3071 -> Vtile [NH][S/32][64][32]
// Tile 256x256, BK=32, 8 waves (2M x 4N), per-wave 128x64.
__global__ __launch_bounds__(512, 2) void gemm_qkv(const u16* __restrict__ A, const u16* __restrict__ B,
                                                   const float* __restrict__ bias,
                                                   u16* __restrict__ Qh, u16* __restrict__ Kh,
                                                   u16* __restrict__ Vtile) {
  __shared__ __align__(16) u16 SA[3][256 * 32];
  __shared__ __align__(16) u16 SB[3][256 * 32];
  const int nwgx = gridDim.x;                        // 12
  const int orig = blockIdx.y * nwgx + blockIdx.x;   // 0..191
  const int cpx = (nwgx * gridDim.y) >> 3;           // 24
  const int wgid = (orig & 7) * cpx + (orig >> 3);   // bijective (192%8==0)
  const int bm = (wgid / nwgx) * 256, bn = (wgid % nwgx) * 256;
  const int tid = threadIdx.x;
  const int lane = tid & 63, wid = tid >> 6;
  const int lrow = lane & 15, lgrp = lane >> 4;
  const int wr = (wid >> 2) * 128, wc = (wid & 3) * 64;

  f32x4 acc[8][4];
  const f32x4 zero = {0.f, 0.f, 0.f, 0.f};
#pragma unroll
  for (int m = 0; m < 8; ++m)
#pragma unroll
    for (int n = 0; n < 4; ++n) acc[m][n] = zero;

  stage_tile(A, B, bm, bn, SA[0], SB[0], 0, tid);
  stage_tile(A, B, bm, bn, SA[1], SB[1], 1, tid);
  asm volatile("s_waitcnt vmcnt(4)" ::: "memory");   // tile0 landed (tile1 may fly)
  asm volatile("s_barrier" ::: "memory");

  for (int t = 0; t < NKT; ++t) {
    const int s = t % 3;
    if (t + 2 < NKT) stage_tile(A, B, bm, bn, SA[(t + 2) % 3], SB[(t + 2) % 3], t + 2, tid);
    bf16x8 af[8], bfr[4];
#pragma unroll
    for (int m = 0; m < 8; ++m)
      af[m] = *reinterpret_cast<const bf16x8*>(&SA[s][(wr + m * 16 + lrow) * 32 + lgrp * 8]);
#pragma unroll
    for (int n = 0; n < 4; ++n)
      bfr[n] = *reinterpret_cast<const bf16x8*>(&SB[s][(wc + n * 16 + lrow) * 32 + lgrp * 8]);
    __builtin_amdgcn_s_setprio(1);
#pragma unroll
    for (int m = 0; m < 8; ++m)
#pragma unroll
      for (int n = 0; n < 4; ++n)
        acc[m][n] = __builtin_amdgcn_mfma_f32_16x16x32_bf16(af[m], bfr[n], acc[m][n], 0, 0, 0);
    __builtin_amdgcn_s_setprio(0);
    // Counted wait: next tile (t+1) landed; the 4 loads of t+2 stay in flight.
    if (t + 2 < NKT) { asm volatile("s_waitcnt vmcnt(4)" ::: "memory"); }
    else if (t + 1 < NKT) { asm volatile("s_waitcnt vmcnt(0)" ::: "memory"); }
    asm volatile("s_barrier" ::: "memory");
  }

#pragma unroll
  for (int m = 0; m < 8; ++m)
#pragma unroll
    for (int n = 0; n < 4; ++n) {
      const int row0 = bm + wr + m * 16 + lgrp * 4;
      const int colg = bn + wc + n * 16 + lrow;
      const float b = bias[colg];
      if (bn < 2048) {
        u16* dst = (bn < 1024) ? Qh : Kh;
        // exp2 trick: fold 1/ln2 into Q's scale.
        const float sc = (bn < 1024) ? 0.18033688f : 1.0f;
        const int hh = (colg & 1023) >> 6;
        const int dd = colg & 63;
#pragma unroll
        for (int r = 0; r < 4; ++r)
          dst[((size_t)hh * SEQ + row0 + r) * HD + dd] = f2bf((acc[m][n][r] + b) * sc);
      } else {
        const int dv = colg - 2048;
        const int hh = dv >> 6, dd = dv & 63;
        u16x4 pk;
#pragma unroll
        for (int r = 0; r < 4; ++r) pk[r] = f2bf(acc[m][n][r] + b);
        u16* vt = Vtile + ((((size_t)hh * NT32 + (row0 >> 5)) * HD + dd) << 5) + (row0 & 31);
        *reinterpret_cast<u16x4*>(vt) = pk;
      }
    }
}

// Banded flash attention, deferred softmax (exp2 domain), SPLIT-K across wave pairs.
// Qh,Kh: [NH][S][64] bf16; Vtile: [NH][S/32][64][32] bf16.
// Block: (32 queries, head) -> 4 waves = 2 q-tiles x 2 key-halves.
__global__ __launch_bounds__(256) void lf_attn(const u16* __restrict__ Qh, const u16* __restrict__ Kh,
                                               const u16* __restrict__ Vtile, const float* __restrict__ amask,
                                               float* __restrict__ out) {
  const int nwgx = gridDim.x;                       // 128
  const int nwg = nwgx * gridDim.y;                 // 2048
  const int orig = blockIdx.y * nwgx + blockIdx.x;
  const int cpx = nwg >> 3;                         // 256
  const int wgid = (orig & 7) * cpx + (orig >> 3);  // bijective (2048%8==0)
  const int h = wgid / nwgx;
  const int q0 = (wgid % nwgx) * 32;
  const int tid = threadIdx.x;
  const int wid = tid >> 6, lane = tid & 63;
  const int qt = wid & 1, kh = wid >> 1;
  const int lrow = lane & 15, lgrp = lane >> 4;
  const int qw = q0 + qt * 16;
  __shared__ __align__(16) u16 Plds[4][16][32];
  __shared__ __align__(16) float Ocmb[2][16][64];
  __shared__ float Pscmb[2][16];

  bf16x8 qf0, qf1;
  {
    const u16* qbase = Qh + ((size_t)h * SEQ + qw + lrow) * HD + lgrp * 8;
    qf0 = *reinterpret_cast<const bf16x8*>(qbase);
    qf1 = *reinterpret_cast<const bf16x8*>(qbase + 32);
  }
  f32x4 zero = {0.f, 0.f, 0.f, 0.f};
  f32x4 o_acc[4];
  float ps[4];
#pragma unroll
  for (int r = 0; r < 4; ++r) ps[r] = 0.f;
#pragma unroll
  for (int g = 0; g < 4; ++g) o_acc[g] = zero;

  int kstart = qw - WIN; if (kstart < 0) kstart = 0; kstart &= ~31;
  int kend = qw + 15 + WIN + 1; kend = (kend + 31) & ~31; if (kend > SEQ) kend = SEQ;
  const int nt = (kend - kstart) >> 5;
  const int hf = (nt + 1) >> 1;
  const int tbeg = kh ? hf : 0;
  const int tend = kh ? nt : hf;

  for (int t = tbeg; t < tend; ++t) {
    const int kt = kstart + t * 32;
    const int j0 = kt + lrow;
    // K fragment loads: 1KB contiguous per instruction.
    const u16* kb0 = Kh + ((size_t)h * SEQ + kt + lrow) * HD + lgrp * 8;
    const bf16x8 k00 = *reinterpret_cast<const bf16x8*>(kb0);
    const bf16x8 k01 = *reinterpret_cast<const bf16x8*>(kb0 + 32);
    const bf16x8 k10 = *reinterpret_cast<const bf16x8*>(kb0 + 16 * HD);
    const bf16x8 k11 = *reinterpret_cast<const bf16x8*>(kb0 + 16 * HD + 32);
    // V fragment prefetch: contiguous 4KB tile.
    const u16* vb = Vtile + (((size_t)h * NT32 + (kt >> 5)) * HD << 5) + lrow * 32 + lgrp * 8;
    bf16x8 vf[4];
#pragma unroll
    for (int g = 0; g < 4; ++g)
      vf[g] = *reinterpret_cast<const bf16x8*>(vb + g * 16 * 32);
    f32x4 s0 = zero, s1 = zero;
    s0 = __builtin_amdgcn_mfma_f32_16x16x32_bf16(qf0, k00, s0, 0, 0, 0);
    s0 = __builtin_amdgcn_mfma_f32_16x16x32_bf16(qf1, k01, s0, 0, 0, 0);
    s1 = __builtin_amdgcn_mfma_f32_16x16x32_bf16(qf0, k10, s1, 0, 0, 0);
    s1 = __builtin_amdgcn_mfma_f32_16x16x32_bf16(qf1, k11, s1, 0, 0, 0);

    // exp2 domain: scores already scaled by 1/ln2 (Q pre-scale); mask too.
    const float am0 = (amask[j0] != 0.f) ? -14426.95f : 0.f;
    const float am1 = (amask[j0 + 16] != 0.f) ? -14426.95f : 0.f;
#pragma unroll
    for (int r = 0; r < 4; ++r) {
      const int i_abs = qw + lgrp * 4 + r;
      const int d0 = j0 - i_abs + WIN;   // valid iff 0 <= d0 <= 2*WIN
      const float e0 = ((unsigned)d0 <= 2u * WIN) ? __builtin_amdgcn_exp2f(s0[r] + am0) : 0.f;
      const float e1 = ((unsigned)(d0 + 16) <= 2u * WIN) ? __builtin_amdgcn_exp2f(s1[r] + am1) : 0.f;
      ps[r] += e0 + e1;
      Plds[wid][lgrp * 4 + r][lrow] = f2bf(e0);
      Plds[wid][lgrp * 4 + r][lrow + 16] = f2bf(e1);
    }
    const bf16x8 pf = *reinterpret_cast<const bf16x8*>(&Plds[wid][lrow][lgrp * 8]);
#pragma unroll
    for (int g = 0; g < 4; ++g)
      o_acc[g] = __builtin_amdgcn_mfma_f32_16x16x32_bf16(pf, vf[g], o_acc[g], 0, 0, 0);
  }

  // 16-lane row-sum reduce of ps (each lane then holds the full row sum).
#pragma unroll
  for (int r = 0; r < 4; ++r) {
#pragma unroll
    for (int off = 1; off < 16; off <<= 1) ps[r] += __shfl_xor(ps[r], off, 16);
  }

  // Combine the two key-halves of each q-tile.
  if (kh == 1) {
#pragma unroll
    for (int g = 0; g < 4; ++g)
#pragma unroll
      for (int r = 0; r < 4; ++r)
        Ocmb[qt][lgrp * 4 + r][g * 16 + lrow] = o_acc[g][r];
    if (lrow == 0) {
#pragma unroll
      for (int r = 0; r < 4; ++r) Pscmb[qt][lgrp * 4 + r] = ps[r];
    }
  }
  __syncthreads();
  if (kh == 0) {
#pragma unroll
    for (int g = 0; g < 4; ++g)
#pragma unroll
      for (int r = 0; r < 4; ++r) {
        const int row = qw + lgrp * 4 + r;
        const float o = o_acc[g][r] + Ocmb[qt][lgrp * 4 + r][g * 16 + lrow];
        const float l = ps[r] + Pscmb[qt][lgrp * 4 + r];
        out[(size_t)row * DIM + h * HD + g * 16 + lrow] = o / l;
      }
  }
}

extern "C" void kernel_launch(void* const* d_in, const int* in_sizes, int n_in,
                              void* d_out, int out_size, void* d_ws, size_t ws_size,
                              hipStream_t stream) {
  const float* hsrc  = (const float*)d_in[0];
  const float* amask = (const float*)d_in[1];
  const float* Wq = (const float*)d_in[3];
  const float* bq = (const float*)d_in[4];
  const float* Wk = (const float*)d_in[5];
  const float* bk = (const float*)d_in[6];
  const float* Wv = (const float*)d_in[7];
  const float* bv = (const float*)d_in[8];
  float* out = (float*)d_out;
  char* ws = (char*)d_ws;
  const size_t MB = 1024 * 1024;
  u16*   Hb      = (u16*)(ws);                 // 8 MB: hidden bf16 [4096][1024]
  u16*   Wcat    = (u16*)(ws + 8 * MB);        // 6 MB: [3072][1024] bf16 (Wq|Wk|Wv)
  float* biascat = (float*)(ws + 14 * MB);     // 12 KB: [3072] f32
  u16*   Qh      = (u16*)(ws + 15 * MB);       // 8 MB: [NH][S][64] (pre-scaled by 0.125/ln2)
  u16*   Kh      = (u16*)(ws + 23 * MB);       // 8 MB: [NH][S][64]
  u16*   Vtile   = (u16*)(ws + 31 * MB);       // 8 MB: [NH][S/32][64][32]

  cast4<<<4096, 256, 0, stream>>>(hsrc, Hb, SEQ * DIM);
  cast4<<<1024, 256, 0, stream>>>(Wq, Wcat, DIM * DIM);
  cast4<<<1024, 256, 0, stream>>>(Wk, Wcat + DIM * DIM, DIM * DIM);
  cast4<<<1024, 256, 0, stream>>>(Wv, Wcat + 2 * DIM * DIM, DIM * DIM);
  (void)hipMemcpyAsync(biascat,            bq, DIM * sizeof(float), hipMemcpyDeviceToDevice, stream);
  (void)hipMemcpyAsync(biascat + DIM,      bk, DIM * sizeof(float), hipMemcpyDeviceToDevice, stream);
  (void)hipMemcpyAsync(biascat + 2 * DIM,  bv, DIM * sizeof(float), hipMemcpyDeviceToDevice, stream);

  dim3 gq(3 * DIM / 256, SEQ / 256);  // (12, 16)
  gemm_qkv<<<gq, 512, 0, stream>>>(Hb, Wcat, biascat, Qh, Kh, Vtile);

  dim3 ga(SEQ / 32, NH);              // (128, 16)
  lf_attn<<<ga, 256, 0, stream>>>(Qh, Kh, Vtile, amask, out);
}

// Round 7
// 106.524 us; speedup vs baseline: 1.3992x; 1.0706x over previous
//
#include <hip/hip_runtime.h>
#include <hip/hip_bf16.h>

typedef unsigned short u16;
typedef __attribute__((ext_vector_type(8))) __bf16 bf16x8;
typedef __attribute__((ext_vector_type(4))) float f32x4;
typedef __attribute__((ext_vector_type(4))) unsigned short u16x4;

#define SEQ 4096
#define DIM 1024
#define NH 16
#define HD 64
#define WIN 256
#define NT32 (SEQ / 32)
#define NKT 32  // K-tiles of 32 in K=1024

__device__ inline u16 f2bf(float f) {
  __hip_bfloat16 h = __float2bfloat16(f);
  return __builtin_bit_cast(u16, h);
}

__device__ inline void gload_lds16(const void* g, void* l) {
  auto gp = reinterpret_cast<__attribute__((address_space(1))) unsigned int*>(
      reinterpret_cast<unsigned long long>(g));
  auto lp = reinterpret_cast<__attribute__((address_space(3))) unsigned int*>(
      reinterpret_cast<unsigned long long>(l));
  __builtin_amdgcn_global_load_lds(gp, lp, 16, 0, 0);
}

__global__ __launch_bounds__(256) void cast4(const float* __restrict__ in,
                                             u16* __restrict__ out, int n) {
  int i = (blockIdx.x * 256 + threadIdx.x) * 4;
  if (i >= n) return;
  const float4 v = *reinterpret_cast<const float4*>(in + i);
  u16x4 r;
  r.x = f2bf(v.x); r.y = f2bf(v.y); r.z = f2bf(v.z); r.w = f2bf(v.w);
  *reinterpret_cast<u16x4*>(out + i) = r;
}

// Fused cast of the 3 weight matrices (each DIM*DIM = 1M elems) into Wcat.
__global__ __launch_bounds__(256) void cast_w3(const float* __restrict__ w0, const float* __restrict__ w1,
                                               const float* __restrict__ w2, u16* __restrict__ out) {
  int i = (blockIdx.x * 256 + threadIdx.x) * 4;
  const int seg = i >> 20;                 // 0,1,2
  const int loc = i & ((1 << 20) - 1);
  const float* src = (seg == 0) ? w0 : (seg == 1) ? w1 : w2;
  const float4 v = *reinterpret_cast<const float4*>(src + loc);
  u16x4 r;
  r.x = f2bf(v.x); r.y = f2bf(v.y); r.z = f2bf(v.z); r.w = f2bf(v.w);
  *reinterpret_cast<u16x4*>(out + i) = r;
}

// Pack 3 bias vectors (DIM each) into one f32 array.
__global__ __launch_bounds__(256) void pack_bias(const float* __restrict__ b0, const float* __restrict__ b1,
                                                 const float* __restrict__ b2, float* __restrict__ out) {
  int i = blockIdx.x * 256 + threadIdx.x;  // 0..3071
  const int seg = i >> 10, loc = i & 1023;
  out[i] = (seg == 0) ? b0[loc] : (seg == 1) ? b1[loc] : b2[loc];
}

// Stage one 256x32 A-panel tile + 256x32 B-panel tile into LDS slot.
__device__ __forceinline__ void stage_tile(const u16* __restrict__ A, const u16* __restrict__ B,
                                           int bm, int bn, u16* sa, u16* sb, int kt, int tid) {
  const int k0 = kt * 32;
#pragma unroll
  for (int l = 0; l < 2; ++l) {
    const int li = l * 512 + tid;         // 1024 chunks of 16B per matrix
    const int r = li >> 2, c = (li & 3) * 8;
    gload_lds16(A + (size_t)(bm + r) * DIM + k0 + c, sa + li * 8);
    gload_lds16(B + (size_t)(bn + r) * DIM + k0 + c, sb + li * 8);
  }
}

// Fused QKV projection, tri-buffered counted-vmcnt pipeline (T3/T4).
__global__ __launch_bounds__(512, 2) void gemm_qkv(const u16* __restrict__ A, const u16* __restrict__ B,
                                                   const float* __restrict__ bias,
                                                   u16* __restrict__ Qh, u16* __restrict__ Kh,
                                                   u16* __restrict__ Vtile) {
  __shared__ __align__(16) u16 SA[3][256 * 32];
  __shared__ __align__(16) u16 SB[3][256 * 32];
  const int nwgx = gridDim.x;                        // 12
  const int orig = blockIdx.y * nwgx + blockIdx.x;   // 0..191
  const int cpx = (nwgx * gridDim.y) >> 3;           // 24
  const int wgid = (orig & 7) * cpx + (orig >> 3);   // bijective (192%8==0)
  const int bm = (wgid / nwgx) * 256, bn = (wgid % nwgx) * 256;
  const int tid = threadIdx.x;
  const int lane = tid & 63, wid = tid >> 6;
  const int lrow = lane & 15, lgrp = lane >> 4;
  const int wr = (wid >> 2) * 128, wc = (wid & 3) * 64;

  f32x4 acc[8][4];
  const f32x4 zero = {0.f, 0.f, 0.f, 0.f};
#pragma unroll
  for (int m = 0; m < 8; ++m)
#pragma unroll
    for (int n = 0; n < 4; ++n) acc[m][n] = zero;

  stage_tile(A, B, bm, bn, SA[0], SB[0], 0, tid);
  stage_tile(A, B, bm, bn, SA[1], SB[1], 1, tid);
  asm volatile("s_waitcnt vmcnt(4)" ::: "memory");   // tile0 landed (tile1 may fly)
  asm volatile("s_barrier" ::: "memory");

  for (int t = 0; t < NKT; ++t) {
    const int s = t % 3;
    if (t + 2 < NKT) stage_tile(A, B, bm, bn, SA[(t + 2) % 3], SB[(t + 2) % 3], t + 2, tid);
    bf16x8 af[8], bfr[4];
#pragma unroll
    for (int m = 0; m < 8; ++m)
      af[m] = *reinterpret_cast<const bf16x8*>(&SA[s][(wr + m * 16 + lrow) * 32 + lgrp * 8]);
#pragma unroll
    for (int n = 0; n < 4; ++n)
      bfr[n] = *reinterpret_cast<const bf16x8*>(&SB[s][(wc + n * 16 + lrow) * 32 + lgrp * 8]);
    __builtin_amdgcn_s_setprio(1);
#pragma unroll
    for (int m = 0; m < 8; ++m)
#pragma unroll
      for (int n = 0; n < 4; ++n)
        acc[m][n] = __builtin_amdgcn_mfma_f32_16x16x32_bf16(af[m], bfr[n], acc[m][n], 0, 0, 0);
    __builtin_amdgcn_s_setprio(0);
    if (t + 2 < NKT) { asm volatile("s_waitcnt vmcnt(4)" ::: "memory"); }
    else if (t + 1 < NKT) { asm volatile("s_waitcnt vmcnt(0)" ::: "memory"); }
    asm volatile("s_barrier" ::: "memory");
  }

#pragma unroll
  for (int m = 0; m < 8; ++m)
#pragma unroll
    for (int n = 0; n < 4; ++n) {
      const int row0 = bm + wr + m * 16 + lgrp * 4;
      const int colg = bn + wc + n * 16 + lrow;
      const float b = bias[colg];
      if (bn < 2048) {
        u16* dst = (bn < 1024) ? Qh : Kh;
        const float sc = (bn < 1024) ? 0.18033688f : 1.0f;  // 0.125/ln2 (exp2 trick)
        const int hh = (colg & 1023) >> 6;
        const int dd = colg & 63;
#pragma unroll
        for (int r = 0; r < 4; ++r)
          dst[((size_t)hh * SEQ + row0 + r) * HD + dd] = f2bf((acc[m][n][r] + b) * sc);
      } else {
        const int dv = colg - 2048;
        const int hh = dv >> 6, dd = dv & 63;
        u16x4 pk;
#pragma unroll
        for (int r = 0; r < 4; ++r) pk[r] = f2bf(acc[m][n][r] + b);
        u16* vt = Vtile + ((((size_t)hh * NT32 + (row0 >> 5)) * HD + dd) << 5) + (row0 & 31);
        *reinterpret_cast<u16x4*>(vt) = pk;
      }
    }
}

// Banded flash attention, deferred softmax (exp2 domain), split-K wave pairs,
// 1-deep register prefetch of K/V/mask, pointer-increment addressing.
__global__ __launch_bounds__(256, 4) void lf_attn(const u16* __restrict__ Qh, const u16* __restrict__ Kh,
                                                  const u16* __restrict__ Vtile, const float* __restrict__ amask,
                                                  float* __restrict__ out) {
  const int nwgx = gridDim.x;                       // 128
  const int nwg = nwgx * gridDim.y;                 // 2048
  const int orig = blockIdx.y * nwgx + blockIdx.x;
  const int cpx = nwg >> 3;                         // 256
  const int wgid = (orig & 7) * cpx + (orig >> 3);  // bijective (2048%8==0)
  const int h = wgid / nwgx;
  const int q0 = (wgid % nwgx) * 32;
  const int tid = threadIdx.x;
  const int wid = tid >> 6, lane = tid & 63;
  const int qt = wid & 1, kh = wid >> 1;
  const int lrow = lane & 15, lgrp = lane >> 4;
  const int qw = q0 + qt * 16;
  __shared__ __align__(16) u16 Plds[4][16][40];     // 80B rows: ~2-way conflicts only
  __shared__ __align__(16) float Ocmb[2][16][64];
  __shared__ float Pscmb[2][16];

  bf16x8 qf0, qf1;
  {
    const u16* qbase = Qh + ((size_t)h * SEQ + qw + lrow) * HD + lgrp * 8;
    qf0 = *reinterpret_cast<const bf16x8*>(qbase);
    qf1 = *reinterpret_cast<const bf16x8*>(qbase + 32);
  }
  const f32x4 zero = {0.f, 0.f, 0.f, 0.f};
  f32x4 o_acc[4];
  float ps[4];
#pragma unroll
  for (int r = 0; r < 4; ++r) ps[r] = 0.f;
#pragma unroll
  for (int g = 0; g < 4; ++g) o_acc[g] = zero;

  int kstart = qw - WIN; if (kstart < 0) kstart = 0; kstart &= ~31;
  int kend = qw + 15 + WIN + 1; kend = (kend + 31) & ~31; if (kend > SEQ) kend = SEQ;
  const int nt = (kend - kstart) >> 5;
  const int hf = (nt + 1) >> 1;
  const int tbeg = kh ? hf : 0;
  const int tend = kh ? nt : hf;

  // Pointer bases for tile tbeg; all advance by 2048 elements (= 32 keys) per tile.
  const u16* kp = Kh + ((size_t)h * SEQ + kstart + tbeg * 32 + lrow) * HD + lgrp * 8;
  const u16* vp = Vtile + ((size_t)h * NT32 + (kstart >> 5) + tbeg) * (HD * 32) + lrow * 32 + lgrp * 8;
  const float* ap = amask + kstart + tbeg * 32 + lrow;

  bf16x8 kf0, kf1, kf2, kf3, vf0, vf1, vf2, vf3;
  float a0, a1;
  kf0 = *reinterpret_cast<const bf16x8*>(kp);
  kf1 = *reinterpret_cast<const bf16x8*>(kp + 32);
  kf2 = *reinterpret_cast<const bf16x8*>(kp + 16 * HD);
  kf3 = *reinterpret_cast<const bf16x8*>(kp + 16 * HD + 32);
  vf0 = *reinterpret_cast<const bf16x8*>(vp);
  vf1 = *reinterpret_cast<const bf16x8*>(vp + 512);
  vf2 = *reinterpret_cast<const bf16x8*>(vp + 1024);
  vf3 = *reinterpret_cast<const bf16x8*>(vp + 1536);
  a0 = ap[0]; a1 = ap[16];

  for (int t = tbeg; t < tend; ++t) {
    const int kt = kstart + t * 32;
    kp += 2048; vp += 2048; ap += 32;
    const bool more = (t + 1 < tend);   // wave-uniform
    bf16x8 kn0, kn1, kn2, kn3, vn0, vn1, vn2, vn3;
    float an0 = 0.f, an1 = 0.f;
    if (more) {  // prefetch next tile (issues before the compute below retires)
      kn0 = *reinterpret_cast<const bf16x8*>(kp);
      kn1 = *reinterpret_cast<const bf16x8*>(kp + 32);
      kn2 = *reinterpret_cast<const bf16x8*>(kp + 16 * HD);
      kn3 = *reinterpret_cast<const bf16x8*>(kp + 16 * HD + 32);
      vn0 = *reinterpret_cast<const bf16x8*>(vp);
      vn1 = *reinterpret_cast<const bf16x8*>(vp + 512);
      vn2 = *reinterpret_cast<const bf16x8*>(vp + 1024);
      vn3 = *reinterpret_cast<const bf16x8*>(vp + 1536);
      an0 = ap[0]; an1 = ap[16];
    }
    f32x4 s0 = zero, s1 = zero;
    s0 = __builtin_amdgcn_mfma_f32_16x16x32_bf16(qf0, kf0, s0, 0, 0, 0);
    s0 = __builtin_amdgcn_mfma_f32_16x16x32_bf16(qf1, kf1, s0, 0, 0, 0);
    s1 = __builtin_amdgcn_mfma_f32_16x16x32_bf16(qf0, kf2, s1, 0, 0, 0);
    s1 = __builtin_amdgcn_mfma_f32_16x16x32_bf16(qf1, kf3, s1, 0, 0, 0);

    const float am0 = (a0 != 0.f) ? -14426.95f : 0.f;
    const float am1 = (a1 != 0.f) ? -14426.95f : 0.f;
    if (kt >= qw - 241 && kt <= qw + 225) {
      // whole tile inside the band for every row: no validity selects
#pragma unroll
      for (int r = 0; r < 4; ++r) {
        const float e0 = __builtin_amdgcn_exp2f(s0[r] + am0);
        const float e1 = __builtin_amdgcn_exp2f(s1[r] + am1);
        ps[r] += e0 + e1;
        Plds[wid][lgrp * 4 + r][lrow] = f2bf(e0);
        Plds[wid][lgrp * 4 + r][lrow + 16] = f2bf(e1);
      }
    } else {
      const int j0 = kt + lrow;
#pragma unroll
      for (int r = 0; r < 4; ++r) {
        const int i_abs = qw + lgrp * 4 + r;
        const int d0 = j0 - i_abs + WIN;   // valid iff 0 <= d0 <= 2*WIN
        const float e0 = ((unsigned)d0 <= 2u * WIN) ? __builtin_amdgcn_exp2f(s0[r] + am0) : 0.f;
        const float e1 = ((unsigned)(d0 + 16) <= 2u * WIN) ? __builtin_amdgcn_exp2f(s1[r] + am1) : 0.f;
        ps[r] += e0 + e1;
        Plds[wid][lgrp * 4 + r][lrow] = f2bf(e0);
        Plds[wid][lgrp * 4 + r][lrow + 16] = f2bf(e1);
      }
    }
    const bf16x8 pf = *reinterpret_cast<const bf16x8*>(&Plds[wid][lrow][lgrp * 8]);
    o_acc[0] = __builtin_amdgcn_mfma_f32_16x16x32_bf16(pf, vf0, o_acc[0], 0, 0, 0);
    o_acc[1] = __builtin_amdgcn_mfma_f32_16x16x32_bf16(pf, vf1, o_acc[1], 0, 0, 0);
    o_acc[2] = __builtin_amdgcn_mfma_f32_16x16x32_bf16(pf, vf2, o_acc[2], 0, 0, 0);
    o_acc[3] = __builtin_amdgcn_mfma_f32_16x16x32_bf16(pf, vf3, o_acc[3], 0, 0, 0);
    if (more) {
      kf0 = kn0; kf1 = kn1; kf2 = kn2; kf3 = kn3;
      vf0 = vn0; vf1 = vn1; vf2 = vn2; vf3 = vn3;
      a0 = an0; a1 = an1;
    }
  }

  // 16-lane row-sum reduce of ps (each lane then holds the full row sum).
#pragma unroll
  for (int r = 0; r < 4; ++r) {
#pragma unroll
    for (int off = 1; off < 16; off <<= 1) ps[r] += __shfl_xor(ps[r], off, 16);
  }

  // Combine the two key-halves of each q-tile.
  if (kh == 1) {
#pragma unroll
    for (int g = 0; g < 4; ++g)
#pragma unroll
      for (int r = 0; r < 4; ++r)
        Ocmb[qt][lgrp * 4 + r][g * 16 + lrow] = o_acc[g][r];
    if (lrow == 0) {
#pragma unroll
      for (int r = 0; r < 4; ++r) Pscmb[qt][lgrp * 4 + r] = ps[r];
    }
  }
  __syncthreads();
  if (kh == 0) {
#pragma unroll
    for (int g = 0; g < 4; ++g)
#pragma unroll
      for (int r = 0; r < 4; ++r) {
        const int row = qw + lgrp * 4 + r;
        const float o = o_acc[g][r] + Ocmb[qt][lgrp * 4 + r][g * 16 + lrow];
        const float l = ps[r] + Pscmb[qt][lgrp * 4 + r];
        out[(size_t)row * DIM + h * HD + g * 16 + lrow] = o / l;
      }
  }
}

extern "C" void kernel_launch(void* const* d_in, const int* in_sizes, int n_in,
                              void* d_out, int out_size, void* d_ws, size_t ws_size,
                              hipStream_t stream) {
  const float* hsrc  = (const float*)d_in[0];
  const float* amask = (const float*)d_in[1];
  const float* Wq = (const float*)d_in[3];
  const float* bq = (const float*)d_in[4];
  const float* Wk = (const float*)d_in[5];
  const float* bk = (const float*)d_in[6];
  const float* Wv = (const float*)d_in[7];
  const float* bv = (const float*)d_in[8];
  float* out = (float*)d_out;
  char* ws = (char*)d_ws;
  const size_t MB = 1024 * 1024;
  u16*   Hb      = (u16*)(ws);                 // 8 MB: hidden bf16 [4096][1024]
  u16*   Wcat    = (u16*)(ws + 8 * MB);        // 6 MB: [3072][1024] bf16 (Wq|Wk|Wv)
  float* biascat = (float*)(ws + 14 * MB);     // 12 KB: [3072] f32
  u16*   Qh      = (u16*)(ws + 15 * MB);       // 8 MB: [NH][S][64] (pre-scaled by 0.125/ln2)
  u16*   Kh      = (u16*)(ws + 23 * MB);       // 8 MB: [NH][S][64]
  u16*   Vtile   = (u16*)(ws + 31 * MB);       // 8 MB: [NH][S/32][64][32]

  cast4<<<4096, 256, 0, stream>>>(hsrc, Hb, SEQ * DIM);
  cast_w3<<<3072, 256, 0, stream>>>(Wq, Wk, Wv, Wcat);
  pack_bias<<<12, 256, 0, stream>>>(bq, bk, bv, biascat);

  dim3 gq(3 * DIM / 256, SEQ / 256);  // (12, 16)
  gemm_qkv<<<gq, 512, 0, stream>>>(Hb, Wcat, biascat, Qh, Kh, Vtile);

  dim3 ga(SEQ / 32, NH);              // (128, 16)
  lf_attn<<<ga, 256, 0, stream>>>(Qh, Kh, Vtile, amask, out);
}